// Round 8
// baseline (331.262 us; speedup 1.0000x reference)
//
#include <hip/hip_runtime.h>
#include <hip/hip_bf16.h>
#include <hip/hip_fp16.h>

// ============================================================================
// GCN forward. CSR-by-dst via fixed-capacity bucketed counting sort (no
// histogram/scan passes); SPLIT gather/dense pipeline:
//   - gather kernels: 8 lanes per node (edge-split), butterfly combine via
//     __shfl_xor, zero LDS, low VGPR -> latency-hiding via high occupancy.
//   - dense kernels: 4 lanes per node (j/f-slices), weights as per-lane
//     float4 reads from global (L1-resident, 12.8KB), no LDS, no SGPR chains.
//
// Algebra: A_hat(xW) = (A_hat x)W, normalization factored as
//   out[d] = dinv[d] * ( sum_{s in N(d)} hs[s] + hs[d] ) + b,  hs = h*dinv[row]
// hs tables fp16 (xs=4.8MB, h2s=6.4MB, h3s=3.2MB, h4s=0.4MB); aggregate
// intermediates fp32 (shared 12.8MB buffer, disjoint lifetimes).
// ============================================================================

#define NBUCK_SHIFT 8            // 256 nodes per bucket
#define CAP         8192         // padded bucket capacity (avg 4096, sigma 64)
#define PART_CHUNK  4096         // edges per partition block (256 thr x 16)

// ---------------- init per-bucket cursors to fixed bases ----------------
__global__ void init_gcur_kernel(int* __restrict__ gcur, int nbuck) {
    int i = threadIdx.x;
    if (i < nbuck) gcur[i] = i * CAP;
}

// ---------------- partition edges into fixed-capacity buckets ----------------
// staged word: (src << 8) | (dst & 255)
__global__ __launch_bounds__(256) void partition_kernel(const int* __restrict__ src,
                                                        const int* __restrict__ dst,
                                                        int* __restrict__ gcur,
                                                        unsigned int* __restrict__ bucketed,
                                                        int n_edges, int nbuck) {
    __shared__ int cnt[512];
    __shared__ int base[512];
    const int t = threadIdx.x;
    for (int i = t; i < 512; i += 256) cnt[i] = 0;
    __syncthreads();
    long long start = (long long)blockIdx.x * PART_CHUNK;
    int sv[16], dv[16], bv[16];
#pragma unroll
    for (int k = 0; k < 16; ++k) {
        long long e = start + (long long)k * 256 + t;
        bool ok = e < n_edges;
        sv[k] = ok ? src[e] : 0;
        dv[k] = ok ? dst[e] : 0;
        bv[k] = ok ? (dv[k] >> NBUCK_SHIFT) : -1;
        if (ok) atomicAdd(&cnt[bv[k]], 1);
    }
    __syncthreads();
    for (int i = t; i < nbuck; i += 256) {
        int c = cnt[i];
        base[i] = c ? atomicAdd(&gcur[i], c) : 0;
    }
    __syncthreads();
    for (int i = t; i < 512; i += 256) cnt[i] = 0;   // reuse as running cursor
    __syncthreads();
#pragma unroll
    for (int k = 0; k < 16; ++k) {
        if (bv[k] >= 0) {
            int pos = base[bv[k]] + atomicAdd(&cnt[bv[k]], 1);
            bucketed[pos] = ((unsigned int)sv[k] << 8) | (unsigned int)(dv[k] & 255);
        }
    }
}

// ---------------- per-bucket CSR finalize: ends=(beg,end), dinv, place -------
__global__ __launch_bounds__(256) void csr_kernel(const unsigned int* __restrict__ bucketed,
                                                  const int* __restrict__ gcur,
                                                  int2* __restrict__ ends,
                                                  float* __restrict__ dinv,
                                                  int* __restrict__ sorted_src,
                                                  int n) {
    __shared__ int ldeg[256];
    __shared__ int lscan[256];
    const int b = blockIdx.x;
    const int t = threadIdx.x;
    const int beg = b * CAP;
    const int end = gcur[b];                 // beg + count(bucket b)
    ldeg[t] = 0;
    __syncthreads();
    for (int e = beg + t; e < end; e += 256) {
        unsigned int p = bucketed[e];
        atomicAdd(&ldeg[p & 255u], 1);
    }
    __syncthreads();
    int v = ldeg[t];
    lscan[t] = v;
    __syncthreads();
    for (int off = 1; off < 256; off <<= 1) {
        int x = (t >= off) ? lscan[t - off] : 0;
        __syncthreads();
        lscan[t] += x;
        __syncthreads();
    }
    int excl = lscan[t] - v;                 // exclusive scan
    int node = (b << NBUCK_SHIFT) + t;
    if (node < n) {
        ends[node] = make_int2(beg + excl, beg + excl + v);
        dinv[node] = rsqrtf((float)v + 1.0f); // +1 self-loop
    }
    __syncthreads();
    lscan[t] = beg + excl;                   // reuse as placement cursor
    __syncthreads();
    for (int e = beg + t; e < end; e += 256) {
        unsigned int p = bucketed[e];
        int pos = atomicAdd(&lscan[p & 255u], 1);
        sorted_src[pos] = (int)(p >> 8);
    }
}

// ---------------- helpers ----------------
__device__ inline void acc8(float* acc, float4 raw) {
    const __half2* h2 = reinterpret_cast<const __half2*>(&raw);
#pragma unroll
    for (int j = 0; j < 4; ++j) {
        float2 v = __half22float2(h2[j]);
        acc[2 * j]     += v.x;
        acc[2 * j + 1] += v.y;
    }
}
__device__ inline float4 pack8(const float* v) {
    float4 out;
    __half2* h2 = reinterpret_cast<__half2*>(&out);
#pragma unroll
    for (int j = 0; j < 4; ++j) h2[j] = __floats2half2_rn(v[2 * j], v[2 * j + 1]);
    return out;
}

// ---------------- xs[node, 0..23] = half(x[node,0..17] * dinv[node]), padded --
__global__ __launch_bounds__(256) void scale_pad18_kernel(const float* __restrict__ x,
                                                          const float* __restrict__ dinv,
                                                          __half* __restrict__ xs, int n) {
    int node = blockIdx.x * 256 + threadIdx.x;
    if (node >= n) return;
    float di = dinv[node];
    const float* xr = x + (long long)node * 18;
    float v[24];
#pragma unroll
    for (int k = 0; k < 18; ++k) v[k] = xr[k] * di;
#pragma unroll
    for (int k = 18; k < 24; ++k) v[k] = 0.0f;
    float4* o = reinterpret_cast<float4*>(xs + (long long)node * 24);
    o[0] = pack8(v);
    o[1] = pack8(v + 8);
    o[2] = pack8(v + 16);
}

// ---------------- gather24: pure gather of xs (8 lanes/node), fp32 out -------
__global__ __launch_bounds__(256) void gather24_kernel(
    const __half* __restrict__ xs,
    const int* __restrict__ sorted_src, const int2* __restrict__ ends,
    float* __restrict__ aggx, int n) {
    long long gt = (long long)blockIdx.x * 256 + threadIdx.x;
    int node = (int)(gt >> 3);
    int l8   = (int)(gt & 7);
    if (node >= n) return;
    int2 be = ends[node];

    float acc[24];
#pragma unroll
    for (int j = 0; j < 24; ++j) acc[j] = 0.0f;
    if (l8 == 7) {
        const float4* pp = reinterpret_cast<const float4*>(xs + (long long)node * 24);
        acc8(acc, pp[0]); acc8(acc + 8, pp[1]); acc8(acc + 16, pp[2]);
    }
    for (int e = be.x + l8; e < be.y; e += 8) {
        int s = sorted_src[e];
        const float4* pp = reinterpret_cast<const float4*>(xs + (long long)s * 24);
        acc8(acc, pp[0]); acc8(acc + 8, pp[1]); acc8(acc + 16, pp[2]);
    }
#pragma unroll
    for (int j = 0; j < 24; ++j) {
        acc[j] += __shfl_xor(acc[j], 1);
        acc[j] += __shfl_xor(acc[j], 2);
        acc[j] += __shfl_xor(acc[j], 4);
    }
    if (l8 < 3) {
        float4* o = reinterpret_cast<float4*>(aggx + (long long)node * 32 + l8 * 8);
        o[0] = make_float4(acc[l8 * 8 + 0], acc[l8 * 8 + 1], acc[l8 * 8 + 2], acc[l8 * 8 + 3]);
        o[1] = make_float4(acc[l8 * 8 + 4], acc[l8 * 8 + 5], acc[l8 * 8 + 6], acc[l8 * 8 + 7]);
    }
}

// ---------------- dense12 (4 lanes/node, global L1 weights) ------------------
// lane owns hidden slice j0=l4*16: hid = relu((a*di)@W1+b1)[j0:j0+16],
// partials out[32] over its 16 j's, 4-lane reduce-scatter, store 8 fp16.
__global__ __launch_bounds__(256) void dense12_kernel(
    const float* __restrict__ aggx, const float* __restrict__ dinv,
    const float* __restrict__ W1, const float* __restrict__ b1,
    const float* __restrict__ W2, __half* __restrict__ h2s, int n) {
    long long gt = (long long)blockIdx.x * 256 + threadIdx.x;
    int node = (int)(gt >> 2);
    int l4   = (int)(gt & 3);
    if (node >= n) return;
    float di = dinv[node];

    const float4* ar = reinterpret_cast<const float4*>(aggx + (long long)node * 32);
    float a[24];
#pragma unroll
    for (int q = 0; q < 6; ++q) {
        float4 v = ar[q];
        a[4 * q] = v.x; a[4 * q + 1] = v.y; a[4 * q + 2] = v.z; a[4 * q + 3] = v.w;
    }
#pragma unroll
    for (int k = 0; k < 18; ++k) a[k] *= di;

    const int j0 = l4 * 16;
    float hid[16];
    {
        const float4* bb = reinterpret_cast<const float4*>(b1 + j0);
#pragma unroll
        for (int q = 0; q < 4; ++q) {
            float4 v = bb[q];
            hid[4 * q] = v.x; hid[4 * q + 1] = v.y; hid[4 * q + 2] = v.z; hid[4 * q + 3] = v.w;
        }
    }
#pragma unroll
    for (int k = 0; k < 18; ++k) {
        const float4* w = reinterpret_cast<const float4*>(W1 + k * 64 + j0);
        float ak = a[k];
#pragma unroll
        for (int q = 0; q < 4; ++q) {
            float4 v = w[q];
            hid[4 * q]     = fmaf(ak, v.x, hid[4 * q]);
            hid[4 * q + 1] = fmaf(ak, v.y, hid[4 * q + 1]);
            hid[4 * q + 2] = fmaf(ak, v.z, hid[4 * q + 2]);
            hid[4 * q + 3] = fmaf(ak, v.w, hid[4 * q + 3]);
        }
    }
#pragma unroll
    for (int jj = 0; jj < 16; ++jj) hid[jj] = fmaxf(hid[jj], 0.0f);

    float out[32];
#pragma unroll
    for (int f = 0; f < 32; ++f) out[f] = 0.0f;
#pragma unroll
    for (int jj = 0; jj < 16; ++jj) {
        const float4* w = reinterpret_cast<const float4*>(W2 + (j0 + jj) * 32);
        float hv = hid[jj];
#pragma unroll
        for (int q = 0; q < 8; ++q) {
            float4 v = w[q];
            out[4 * q]     = fmaf(hv, v.x, out[4 * q]);
            out[4 * q + 1] = fmaf(hv, v.y, out[4 * q + 1]);
            out[4 * q + 2] = fmaf(hv, v.z, out[4 * q + 2]);
            out[4 * q + 3] = fmaf(hv, v.w, out[4 * q + 3]);
        }
    }
    // reduce-scatter out[32] -> lane l4 owns [8*l4, 8*l4+8)
    const bool hi2 = (l4 & 2);
    float h16[16];
#pragma unroll
    for (int v = 0; v < 16; ++v) {
        float keep = hi2 ? out[16 + v] : out[v];
        float send = hi2 ? out[v] : out[16 + v];
        h16[v] = keep + __shfl_xor(send, 2);
    }
    const bool hi1 = (l4 & 1);
    float q8[8];
#pragma unroll
    for (int v = 0; v < 8; ++v) {
        float keep = hi1 ? h16[8 + v] : h16[v];
        float send = hi1 ? h16[v] : h16[8 + v];
        q8[v] = (keep + __shfl_xor(send, 1)) * di;
    }
    *reinterpret_cast<float4*>(h2s + (long long)node * 32 + l4 * 8) = pack8(q8);
}

// ---------------- gather32: pure gather of h2s (8 lanes/node), fp32 out ------
__global__ __launch_bounds__(256) void gather32_kernel(
    const __half* __restrict__ h2s,
    const int* __restrict__ sorted_src, const int2* __restrict__ ends,
    float* __restrict__ agg2, int n) {
    long long gt = (long long)blockIdx.x * 256 + threadIdx.x;
    int node = (int)(gt >> 3);
    int l8   = (int)(gt & 7);
    if (node >= n) return;
    int2 be = ends[node];

    float acc[32];
#pragma unroll
    for (int j = 0; j < 32; ++j) acc[j] = 0.0f;
    if (l8 == 7) {
        const float4* pp = reinterpret_cast<const float4*>(h2s + (long long)node * 32);
        acc8(acc, pp[0]); acc8(acc + 8, pp[1]); acc8(acc + 16, pp[2]); acc8(acc + 24, pp[3]);
    }
    for (int e = be.x + l8; e < be.y; e += 8) {
        int s = sorted_src[e];
        const float4* pp = reinterpret_cast<const float4*>(h2s + (long long)s * 32);
        acc8(acc, pp[0]); acc8(acc + 8, pp[1]); acc8(acc + 16, pp[2]); acc8(acc + 24, pp[3]);
    }
    // reduce-scatter acc[32] over 8 lanes -> lane owns [4*l8, 4*l8+4)
    const bool hi4 = (l8 & 4);
    float h16[16];
#pragma unroll
    for (int v = 0; v < 16; ++v) {
        float keep = hi4 ? acc[16 + v] : acc[v];
        float send = hi4 ? acc[v] : acc[16 + v];
        h16[v] = keep + __shfl_xor(send, 4);
    }
    const bool hi2 = (l8 & 2);
    float h8[8];
#pragma unroll
    for (int v = 0; v < 8; ++v) {
        float keep = hi2 ? h16[8 + v] : h16[v];
        float send = hi2 ? h16[v] : h16[8 + v];
        h8[v] = keep + __shfl_xor(send, 2);
    }
    const bool hi1 = (l8 & 1);
    float k4[4];
#pragma unroll
    for (int v = 0; v < 4; ++v) {
        float keep = hi1 ? h8[4 + v] : h8[v];
        float send = hi1 ? h8[v] : h8[4 + v];
        k4[v] = keep + __shfl_xor(send, 1);
    }
    *reinterpret_cast<float4*>(agg2 + (long long)node * 32 + l8 * 4) =
        make_float4(k4[0], k4[1], k4[2], k4[3]);
}

// ---------------- dense3 (4 lanes/node, global L1 weights) -------------------
// lane owns f-slice f0=l4*4: out = (relu(a*di+b2) @ W3)[f0:f0+4] * di.
__global__ __launch_bounds__(256) void dense3_kernel(
    const float* __restrict__ agg2, const float* __restrict__ dinv,
    const float* __restrict__ b2, const float* __restrict__ W3,
    __half* __restrict__ h3s, int n) {
    long long gt = (long long)blockIdx.x * 256 + threadIdx.x;
    int node = (int)(gt >> 2);
    int l4   = (int)(gt & 3);
    if (node >= n) return;
    float di = dinv[node];

    const float4* ar = reinterpret_cast<const float4*>(agg2 + (long long)node * 32);
    const float4* bb = reinterpret_cast<const float4*>(b2);
    float v[32];
#pragma unroll
    for (int q = 0; q < 8; ++q) {
        float4 av = ar[q];
        float4 bv = bb[q];
        v[4 * q]     = fmaxf(fmaf(av.x, di, bv.x), 0.0f);
        v[4 * q + 1] = fmaxf(fmaf(av.y, di, bv.y), 0.0f);
        v[4 * q + 2] = fmaxf(fmaf(av.z, di, bv.z), 0.0f);
        v[4 * q + 3] = fmaxf(fmaf(av.w, di, bv.w), 0.0f);
    }
    const int f0 = l4 * 4;
    float o0 = 0.0f, o1 = 0.0f, o2 = 0.0f, o3 = 0.0f;
#pragma unroll
    for (int k = 0; k < 32; ++k) {
        float4 w = *reinterpret_cast<const float4*>(W3 + k * 16 + f0);
        o0 = fmaf(v[k], w.x, o0);
        o1 = fmaf(v[k], w.y, o1);
        o2 = fmaf(v[k], w.z, o2);
        o3 = fmaf(v[k], w.w, o3);
    }
    union { float2 f2; __half2 h2[2]; } u;
    u.h2[0] = __floats2half2_rn(o0 * di, o1 * di);
    u.h2[1] = __floats2half2_rn(o2 * di, o3 * di);
    *reinterpret_cast<float2*>(h3s + (long long)node * 16 + f0) = u.f2;
}

// ---------------- fused layer 4 (4 lanes/node, tiny weights) -----------------
__global__ __launch_bounds__(256) void layer4_kernel(
    const __half* __restrict__ h3s, const float* __restrict__ dinv,
    const int* __restrict__ sorted_src, const int2* __restrict__ ends,
    const float* __restrict__ b3, const float* __restrict__ W4,
    __half* __restrict__ h4s, int n) {
    __shared__ float sW4[32];
    __shared__ float sB3[16];
    for (int i = threadIdx.x; i < 32; i += 256) sW4[i] = W4[i];
    for (int i = threadIdx.x; i < 16; i += 256) sB3[i] = b3[i];
    __syncthreads();

    long long gt = (long long)blockIdx.x * 256 + threadIdx.x;
    int node = (int)(gt >> 2);
    int l4   = (int)(gt & 3);
    if (node >= n) return;
    int2 be = ends[node];
    float di = dinv[node];

    float acc[16];
#pragma unroll
    for (int j = 0; j < 16; ++j) acc[j] = 0.0f;
    if (l4 == 3) {
        const float4* pp = reinterpret_cast<const float4*>(h3s + (long long)node * 16);
        acc8(acc, pp[0]); acc8(acc + 8, pp[1]);
    }
    for (int e = be.x + l4; e < be.y; e += 4) {
        int s = sorted_src[e];
        const float4* pp = reinterpret_cast<const float4*>(h3s + (long long)s * 16);
        acc8(acc, pp[0]); acc8(acc + 8, pp[1]);
    }
    const bool hi2 = (l4 & 2);
    float h8[8];
#pragma unroll
    for (int v = 0; v < 8; ++v) {
        float keep = hi2 ? acc[8 + v] : acc[v];
        float send = hi2 ? acc[v] : acc[8 + v];
        h8[v] = keep + __shfl_xor(send, 2);
    }
    const bool hi1 = (l4 & 1);
    float k4[4];
#pragma unroll
    for (int v = 0; v < 4; ++v) {
        float keep = hi1 ? h8[4 + v] : h8[v];
        float send = hi1 ? h8[v] : h8[4 + v];
        k4[v] = keep + __shfl_xor(send, 1);
    }
    const int k0 = l4 * 4;
    float o0 = 0.0f, o1 = 0.0f;
#pragma unroll
    for (int kk = 0; kk < 4; ++kk) {
        float v = fmaxf(fmaf(k4[kk], di, sB3[k0 + kk]), 0.0f);
        o0 = fmaf(v, sW4[2 * (k0 + kk)], o0);
        o1 = fmaf(v, sW4[2 * (k0 + kk) + 1], o1);
    }
    o0 += __shfl_xor(o0, 1); o0 += __shfl_xor(o0, 2);
    o1 += __shfl_xor(o1, 1); o1 += __shfl_xor(o1, 2);
    if (l4 == 0)
        *reinterpret_cast<__half2*>(h4s + 2LL * node) = __floats2half2_rn(o0 * di, o1 * di);
}

// ---------------- final: F=2 aggregation + log_softmax (4 lanes/node) --------
__global__ __launch_bounds__(256) void agg2_lsm_kernel(
    const __half* __restrict__ hs, const float* __restrict__ dinv,
    const int* __restrict__ sorted_src, const int2* __restrict__ ends,
    const float* __restrict__ b, float* __restrict__ out, int n) {
    long long gt = (long long)blockIdx.x * 256 + threadIdx.x;
    int node = (int)(gt >> 2);
    int l4   = (int)(gt & 3);
    if (node >= n) return;
    int2 be = ends[node];
    float ax = 0.0f, ay = 0.0f;
    if (l4 == 3) {
        float2 r = __half22float2(*reinterpret_cast<const __half2*>(hs + 2LL * node));
        ax += r.x; ay += r.y;
    }
    for (int e = be.x + l4; e < be.y; e += 4) {
        int s = sorted_src[e];
        float2 r = __half22float2(*reinterpret_cast<const __half2*>(hs + 2LL * s));
        ax += r.x; ay += r.y;
    }
    ax += __shfl_xor(ax, 1); ax += __shfl_xor(ax, 2);
    ay += __shfl_xor(ay, 1); ay += __shfl_xor(ay, 2);
    if (l4 == 0) {
        float di = dinv[node];
        float a = ax * di + b[0];
        float c = ay * di + b[1];
        float m = fmaxf(a, c);
        float lse = m + logf(expf(a - m) + expf(c - m));
        float2 r = make_float2(a - lse, c - lse);
        *reinterpret_cast<float2*>(out + 2LL * node) = r;
    }
}

static inline int cdiv_ll(long long a, int b) { return (int)((a + b - 1) / b); }
static inline char* align16(char* p) { return (char*)(((uintptr_t)p + 15) & ~(uintptr_t)15); }

extern "C" void kernel_launch(void* const* d_in, const int* in_sizes, int n_in,
                              void* d_out, int out_size, void* d_ws, size_t ws_size,
                              hipStream_t stream) {
    (void)n_in; (void)out_size; (void)ws_size;

    const float* x  = (const float*)d_in[0];      // [N,18]
    const int*   ei = (const int*)d_in[1];        // [2,E]
    const float* W1 = (const float*)d_in[2];
    const float* b1 = (const float*)d_in[3];
    const float* W2 = (const float*)d_in[4];
    const float* b2 = (const float*)d_in[5];
    const float* W3 = (const float*)d_in[6];
    const float* b3 = (const float*)d_in[7];
    const float* W4 = (const float*)d_in[8];
    const float* b4 = (const float*)d_in[9];

    const int n = in_sizes[0] / 18;               // 100000
    const int E = in_sizes[1] / 2;                // 1600000
    const int* src = ei;
    const int* dst = ei + E;
    const int nbuck = (n + 255) >> NBUCK_SHIFT;   // 391

    // ---- workspace layout (16B-aligned regions) ----
    char* p = (char*)d_ws;
    int*    gcur       = (int*)p;            p = align16(p + 512 * 4);
    int2*   ends       = (int2*)p;           p = align16(p + (size_t)n * 8);
    float*  dinv       = (float*)p;          p = align16(p + (size_t)n * 4);
    int*    sorted_src = (int*)p;            p = align16(p + (size_t)nbuck * CAP * 4);  // 12.8MB padded
    unsigned int* bucketed = (unsigned int*)p; p = align16(p + (size_t)nbuck * CAP * 4); // 12.8MB padded
    __half* xs         = (__half*)p;         p = align16(p + (size_t)n * 24 * 2);  // 4.8MB
    __half* h2s        = (__half*)p;         p = align16(p + (size_t)n * 32 * 2);  // 6.4MB
    __half* h3s        = (__half*)p;         p = align16(p + (size_t)n * 16 * 2);  // 3.2MB
    __half* h4s        = (__half*)p;         p = align16(p + (size_t)n * 2 * 2);   // 0.4MB
    float*  aggbuf     = (float*)p;          p = align16(p + (size_t)n * 32 * 4);  // 12.8MB

    const int B = 256;
    const int NODE_BLOCKS  = cdiv_ll(n, B);
    const int NODE4_BLOCKS = cdiv_ll(4LL * n, B);
    const int NODE8_BLOCKS = cdiv_ll(8LL * n, B);

    // ---- CSR-by-dst via fixed-capacity bucketed sort (no hist/scan) ----
    init_gcur_kernel<<<1, 512, 0, stream>>>(gcur, nbuck);
    partition_kernel<<<cdiv_ll(E, PART_CHUNK), B, 0, stream>>>(src, dst, gcur, bucketed, E, nbuck);
    csr_kernel<<<nbuck, B, 0, stream>>>(bucketed, gcur, ends, dinv, sorted_src, n);

    // ---- layers 1+2: gather (8 lanes/node) then dense (4 lanes/node) ----
    scale_pad18_kernel<<<NODE_BLOCKS, B, 0, stream>>>(x, dinv, xs, n);
    gather24_kernel<<<NODE8_BLOCKS, B, 0, stream>>>(xs, sorted_src, ends, aggbuf, n);
    dense12_kernel<<<NODE4_BLOCKS, B, 0, stream>>>(aggbuf, dinv, W1, b1, W2, h2s, n);

    // ---- layer 3: gather then dense ----
    gather32_kernel<<<NODE8_BLOCKS, B, 0, stream>>>(h2s, sorted_src, ends, aggbuf, n);
    dense3_kernel<<<NODE4_BLOCKS, B, 0, stream>>>(aggbuf, dinv, b2, W3, h3s, n);

    // ---- layer 4 (fused, tiny) + final aggregation/log_softmax ----
    layer4_kernel<<<NODE4_BLOCKS, B, 0, stream>>>(h3s, dinv, sorted_src, ends, b3, W4, h4s, n);
    agg2_lsm_kernel<<<NODE4_BLOCKS, B, 0, stream>>>(h4s, dinv, sorted_src, ends, b4, (float*)d_out, n);
}

// Round 9
// 206.199 us; speedup vs baseline: 1.6065x; 1.6065x over previous
//
#include <hip/hip_runtime.h>
#include <hip/hip_bf16.h>
#include <hip/hip_fp16.h>

// ============================================================================
// GCN forward. CSR-by-dst via fixed-capacity bucketed counting sort (no
// histogram/scan); fused gather+dense layer kernels, 4 lanes/node:
//   - gather: edge-split across the 4 lanes, __shfl_xor (DPP) combine.
//   - dense: LDS weights read as ds_read_b128, conflict-free:
//       * stage-1 (18->64): j-split, lane stride 16 floats -> 2-way (free).
//       * stage-2 (64->32) & layer3 (32->16): f-split, lane stride 8/4 floats
//         -> 4 distinct banks; hidden values exchanged via intra-quad
//         __shfl_xor(1/2/3) = DPP quad_perm (no LDS traffic).
//
// Algebra: A_hat(xW) = (A_hat x)W, normalization factored as
//   out[d] = dinv[d] * ( sum_{s in N(d)} hs[s] + hs[d] ) + b,  hs = h*dinv[row]
// hs tables fp16 (fp32 accumulation): xs=4.8MB, h2s=6.4MB, h3s=3.2MB.
// ============================================================================

#define NBUCK_SHIFT 8            // 256 nodes per bucket
#define CAP         8192         // bucket capacity (avg 4096, sigma ~64)
#define PART_CHUNK  4096         // edges per partition block (256 thr x 16)

// ---------------- init per-bucket cursors to fixed bases ----------------
__global__ void init_gcur_kernel(int* __restrict__ gcur, int nbuck) {
    int i = threadIdx.x;
    if (i < nbuck) gcur[i] = i * CAP;
}

// ---------------- partition edges into fixed-capacity buckets ----------------
// staged word: (src << 8) | (dst & 255)
__global__ __launch_bounds__(256) void partition_kernel(const int* __restrict__ src,
                                                        const int* __restrict__ dst,
                                                        int* __restrict__ gcur,
                                                        unsigned int* __restrict__ bucketed,
                                                        int n_edges, int nbuck) {
    __shared__ int cnt[512];
    __shared__ int base[512];
    const int t = threadIdx.x;
    for (int i = t; i < 512; i += 256) cnt[i] = 0;
    __syncthreads();
    long long start = (long long)blockIdx.x * PART_CHUNK;
    int sv[16], dv[16], bv[16];
#pragma unroll
    for (int k = 0; k < 16; ++k) {
        long long e = start + (long long)k * 256 + t;
        bool ok = e < n_edges;
        sv[k] = ok ? src[e] : 0;
        dv[k] = ok ? dst[e] : 0;
        bv[k] = ok ? (dv[k] >> NBUCK_SHIFT) : -1;
        if (ok) atomicAdd(&cnt[bv[k]], 1);
    }
    __syncthreads();
    for (int i = t; i < nbuck; i += 256) {
        int c = cnt[i];
        base[i] = c ? atomicAdd(&gcur[i], c) : 0;
    }
    __syncthreads();
    for (int i = t; i < 512; i += 256) cnt[i] = 0;   // reuse as running cursor
    __syncthreads();
#pragma unroll
    for (int k = 0; k < 16; ++k) {
        if (bv[k] >= 0) {
            int pos = base[bv[k]] + atomicAdd(&cnt[bv[k]], 1);
            bucketed[pos] = ((unsigned int)sv[k] << 8) | (unsigned int)(dv[k] & 255);
        }
    }
}

// ---------------- per-bucket CSR finalize: ends=(beg,end), dinv, place -------
__global__ __launch_bounds__(256) void csr_kernel(const unsigned int* __restrict__ bucketed,
                                                  const int* __restrict__ gcur,
                                                  int2* __restrict__ ends,
                                                  float* __restrict__ dinv,
                                                  int* __restrict__ sorted_src,
                                                  int n) {
    __shared__ int ldeg[256];
    __shared__ int lscan[256];
    const int b = blockIdx.x;
    const int t = threadIdx.x;
    const int beg = b * CAP;
    const int end = gcur[b];                 // beg + count(bucket b)
    ldeg[t] = 0;
    __syncthreads();
    for (int e = beg + t; e < end; e += 256) {
        unsigned int p = bucketed[e];
        atomicAdd(&ldeg[p & 255u], 1);
    }
    __syncthreads();
    int v = ldeg[t];
    lscan[t] = v;
    __syncthreads();
    for (int off = 1; off < 256; off <<= 1) {
        int x = (t >= off) ? lscan[t - off] : 0;
        __syncthreads();
        lscan[t] += x;
        __syncthreads();
    }
    int excl = lscan[t] - v;                 // exclusive scan
    int node = (b << NBUCK_SHIFT) + t;
    if (node < n) {
        ends[node] = make_int2(beg + excl, beg + excl + v);
        dinv[node] = rsqrtf((float)v + 1.0f); // +1 self-loop
    }
    __syncthreads();
    lscan[t] = beg + excl;                   // reuse as placement cursor
    __syncthreads();
    for (int e = beg + t; e < end; e += 256) {
        unsigned int p = bucketed[e];
        int pos = atomicAdd(&lscan[p & 255u], 1);
        sorted_src[pos] = (int)(p >> 8);
    }
}

// ---------------- helpers ----------------
__device__ inline void acc8(float* acc, float4 raw) {
    const __half2* h2 = reinterpret_cast<const __half2*>(&raw);
#pragma unroll
    for (int j = 0; j < 4; ++j) {
        float2 v = __half22float2(h2[j]);
        acc[2 * j]     += v.x;
        acc[2 * j + 1] += v.y;
    }
}
__device__ inline float4 pack8(const float* v) {
    float4 out;
    __half2* h2 = reinterpret_cast<__half2*>(&out);
#pragma unroll
    for (int j = 0; j < 4; ++j) h2[j] = __floats2half2_rn(v[2 * j], v[2 * j + 1]);
    return out;
}

// ---------------- xs[node, 0..23] = half(x[node,0..17] * dinv[node]), padded --
__global__ __launch_bounds__(256) void scale_pad18_kernel(const float* __restrict__ x,
                                                          const float* __restrict__ dinv,
                                                          __half* __restrict__ xs, int n) {
    int node = blockIdx.x * 256 + threadIdx.x;
    if (node >= n) return;
    float di = dinv[node];
    const float* xr = x + (long long)node * 18;
    float v[24];
#pragma unroll
    for (int k = 0; k < 18; ++k) v[k] = xr[k] * di;
#pragma unroll
    for (int k = 18; k < 24; ++k) v[k] = 0.0f;
    float4* o = reinterpret_cast<float4*>(xs + (long long)node * 24);
    o[0] = pack8(v);
    o[1] = pack8(v + 8);
    o[2] = pack8(v + 16);
}

// ---------------- fused layer 1+2 (4 lanes/node) ----------------------------
// gather(18, edge-split) -> allreduce -> 18->64 relu (j-split, b128 LDS)
// -> 64->32 (f-split, DPP hid exchange, b128 LDS) -> lane stores 8 fp16.
__global__ __launch_bounds__(256) void layer12_kernel(
    const __half* __restrict__ xs, const float* __restrict__ dinv,
    const int* __restrict__ sorted_src, const int2* __restrict__ ends,
    const float* __restrict__ W1, const float* __restrict__ b1,
    const float* __restrict__ W2, __half* __restrict__ h2s, int n) {
    __shared__ float sW1[18 * 64];   // unpadded: j0 stride 16 -> 2-way (free)
    __shared__ float sB1[64];
    __shared__ float sW2[64 * 32];   // unpadded: f0 stride 8 -> 4 banks, clean
    for (int i = threadIdx.x; i < 18 * 64; i += 256) sW1[i] = W1[i];
    for (int i = threadIdx.x; i < 64; i += 256) sB1[i] = b1[i];
    for (int i = threadIdx.x; i < 64 * 32; i += 256) sW2[i] = W2[i];
    __syncthreads();
    const float4* sW1v = reinterpret_cast<const float4*>(sW1);
    const float4* sW2v = reinterpret_cast<const float4*>(sW2);

    long long gt = (long long)blockIdx.x * 256 + threadIdx.x;
    int node = (int)(gt >> 2);
    int l4   = (int)(gt & 3);
    if (node >= n) return;
    int2 be = ends[node];
    float di = dinv[node];

    // ---- gather (edge-split) ----
    float acc[24];
#pragma unroll
    for (int j = 0; j < 24; ++j) acc[j] = 0.0f;
    if (l4 == 3) {   // lane 3 has the fewest edges; give it the self row
        const float4* pp = reinterpret_cast<const float4*>(xs + (long long)node * 24);
        acc8(acc, pp[0]); acc8(acc + 8, pp[1]); acc8(acc + 16, pp[2]);
    }
    for (int e = be.x + l4; e < be.y; e += 4) {
        int s = sorted_src[e];
        const float4* pp = reinterpret_cast<const float4*>(xs + (long long)s * 24);
        acc8(acc, pp[0]); acc8(acc + 8, pp[1]); acc8(acc + 16, pp[2]);
    }
#pragma unroll
    for (int j = 0; j < 18; ++j) {       // all-reduce (DPP)
        acc[j] += __shfl_xor(acc[j], 1);
        acc[j] += __shfl_xor(acc[j], 2);
        acc[j] *= di;                    // fold *di once here
    }

    // ---- stage 1: hidden slice j0 = l4*16 (b128 LDS, 2-way free) ----
    const int j0 = l4 * 16;
    float hid[16];
#pragma unroll
    for (int jj = 0; jj < 16; ++jj) hid[jj] = sB1[j0 + jj];
#pragma unroll
    for (int k = 0; k < 18; ++k) {
        float ak = acc[k];
#pragma unroll
        for (int q = 0; q < 4; ++q) {
            float4 w = sW1v[(k * 64 + j0) / 4 + q];
            hid[4 * q]     = fmaf(ak, w.x, hid[4 * q]);
            hid[4 * q + 1] = fmaf(ak, w.y, hid[4 * q + 1]);
            hid[4 * q + 2] = fmaf(ak, w.z, hid[4 * q + 2]);
            hid[4 * q + 3] = fmaf(ak, w.w, hid[4 * q + 3]);
        }
    }
#pragma unroll
    for (int jj = 0; jj < 16; ++jj) hid[jj] = fmaxf(hid[jj], 0.0f);

    // ---- stage 2: f-split (f0 = l4*8); hid exchanged via DPP quad_perm ----
    const int f0 = l4 * 8;
    float out[8];
#pragma unroll
    for (int f = 0; f < 8; ++f) out[f] = 0.0f;
#pragma unroll
    for (int jj = 0; jj < 16; ++jj) {
        float h0 = hid[jj];
        float h1 = __shfl_xor(h0, 1);
        float h2 = __shfl_xor(h0, 2);
        float h3 = __shfl_xor(h0, 3);
        // value h_m came from lane l4^m -> j = (l4^m)*16 + jj
        const float hv[4] = {h0, h1, h2, h3};
#pragma unroll
        for (int m = 0; m < 4; ++m) {
            int j = ((l4 ^ m) * 16 + jj);
            float4 w0 = sW2v[(j * 32 + f0) / 4];
            float4 w1 = sW2v[(j * 32 + f0) / 4 + 1];
            float h = hv[m];
            out[0] = fmaf(h, w0.x, out[0]);
            out[1] = fmaf(h, w0.y, out[1]);
            out[2] = fmaf(h, w0.z, out[2]);
            out[3] = fmaf(h, w0.w, out[3]);
            out[4] = fmaf(h, w1.x, out[4]);
            out[5] = fmaf(h, w1.y, out[5]);
            out[6] = fmaf(h, w1.z, out[6]);
            out[7] = fmaf(h, w1.w, out[7]);
        }
    }
#pragma unroll
    for (int f = 0; f < 8; ++f) out[f] *= di;
    *reinterpret_cast<float4*>(h2s + (long long)node * 32 + f0) = pack8(out);
}

// ---------------- fused layer 3 (4 lanes/node) ------------------------------
// gather(32, edge-split) -> reduce-scatter (lane owns 8 k's) -> relu(+b2)
// -> 32->16 f-split (DPP exchange, b128 LDS) -> lane stores 4 fp16.
__global__ __launch_bounds__(256) void layer3_kernel(
    const __half* __restrict__ h2s, const float* __restrict__ dinv,
    const int* __restrict__ sorted_src, const int2* __restrict__ ends,
    const float* __restrict__ b2, const float* __restrict__ W3,
    __half* __restrict__ h3s, int n) {
    __shared__ float sW3[32 * 16];   // unpadded: f0 stride 4 -> 4 banks, clean
    __shared__ float sB2[32];
    for (int i = threadIdx.x; i < 32 * 16; i += 256) sW3[i] = W3[i];
    for (int i = threadIdx.x; i < 32; i += 256) sB2[i] = b2[i];
    __syncthreads();
    const float4* sW3v = reinterpret_cast<const float4*>(sW3);

    long long gt = (long long)blockIdx.x * 256 + threadIdx.x;
    int node = (int)(gt >> 2);
    int l4   = (int)(gt & 3);
    if (node >= n) return;
    int2 be = ends[node];
    float di = dinv[node];

    float acc[32];
#pragma unroll
    for (int j = 0; j < 32; ++j) acc[j] = 0.0f;
    if (l4 == 3) {
        const float4* pp = reinterpret_cast<const float4*>(h2s + (long long)node * 32);
        acc8(acc, pp[0]); acc8(acc + 8, pp[1]); acc8(acc + 16, pp[2]); acc8(acc + 24, pp[3]);
    }
    for (int e = be.x + l4; e < be.y; e += 4) {
        int s = sorted_src[e];
        const float4* pp = reinterpret_cast<const float4*>(h2s + (long long)s * 32);
        acc8(acc, pp[0]); acc8(acc + 8, pp[1]); acc8(acc + 16, pp[2]); acc8(acc + 24, pp[3]);
    }
    // reduce-scatter acc[32] -> lane owns k in [8*l4, 8*l4+8)
    const bool hi2 = (l4 & 2);
    float h16[16];
#pragma unroll
    for (int v = 0; v < 16; ++v) {
        float keep = hi2 ? acc[16 + v] : acc[v];
        float send = hi2 ? acc[v] : acc[16 + v];
        h16[v] = keep + __shfl_xor(send, 2);
    }
    const bool hi1 = (l4 & 1);
    float k8[8];
#pragma unroll
    for (int v = 0; v < 8; ++v) {
        float keep = hi1 ? h16[8 + v] : h16[v];
        float send = hi1 ? h16[v] : h16[8 + v];
        k8[v] = keep + __shfl_xor(send, 1);
    }

    // ---- dense: f-split (f0 = l4*4); k-values exchanged via DPP ----
    const int k0 = l4 * 8;
    const int f0 = l4 * 4;
    float out[4] = {0.0f, 0.0f, 0.0f, 0.0f};
#pragma unroll
    for (int kk = 0; kk < 8; ++kk) {
        float v0 = fmaxf(fmaf(k8[kk], di, sB2[k0 + kk]), 0.0f);  // relu(acc*di+b2)
        float v1 = __shfl_xor(v0, 1);
        float v2 = __shfl_xor(v0, 2);
        float v3 = __shfl_xor(v0, 3);
        const float vv[4] = {v0, v1, v2, v3};
#pragma unroll
        for (int m = 0; m < 4; ++m) {
            int k = (l4 ^ m) * 8 + kk;
            float4 w = sW3v[k * 4 + l4];          // = (k*16 + f0)/4
            out[0] = fmaf(vv[m], w.x, out[0]);
            out[1] = fmaf(vv[m], w.y, out[1]);
            out[2] = fmaf(vv[m], w.z, out[2]);
            out[3] = fmaf(vv[m], w.w, out[3]);
        }
    }
    union { float2 f2; __half2 h2[2]; } u;
    u.h2[0] = __floats2half2_rn(out[0] * di, out[1] * di);
    u.h2[1] = __floats2half2_rn(out[2] * di, out[3] * di);
    *reinterpret_cast<float2*>(h3s + (long long)node * 16 + f0) = u.f2;
}

// ---------------- fused layer 4 (4 lanes/node, tiny weights) -----------------
__global__ __launch_bounds__(256) void layer4_kernel(
    const __half* __restrict__ h3s, const float* __restrict__ dinv,
    const int* __restrict__ sorted_src, const int2* __restrict__ ends,
    const float* __restrict__ b3, const float* __restrict__ W4,
    __half* __restrict__ h4s, int n) {
    __shared__ float sW4[32];
    __shared__ float sB3[16];
    for (int i = threadIdx.x; i < 32; i += 256) sW4[i] = W4[i];
    for (int i = threadIdx.x; i < 16; i += 256) sB3[i] = b3[i];
    __syncthreads();

    long long gt = (long long)blockIdx.x * 256 + threadIdx.x;
    int node = (int)(gt >> 2);
    int l4   = (int)(gt & 3);
    if (node >= n) return;
    int2 be = ends[node];
    float di = dinv[node];

    float acc[16];
#pragma unroll
    for (int j = 0; j < 16; ++j) acc[j] = 0.0f;
    if (l4 == 3) {
        const float4* pp = reinterpret_cast<const float4*>(h3s + (long long)node * 16);
        acc8(acc, pp[0]); acc8(acc + 8, pp[1]);
    }
    for (int e = be.x + l4; e < be.y; e += 4) {
        int s = sorted_src[e];
        const float4* pp = reinterpret_cast<const float4*>(h3s + (long long)s * 16);
        acc8(acc, pp[0]); acc8(acc + 8, pp[1]);
    }
    const bool hi2 = (l4 & 2);
    float h8[8];
#pragma unroll
    for (int v = 0; v < 8; ++v) {
        float keep = hi2 ? acc[8 + v] : acc[v];
        float send = hi2 ? acc[v] : acc[8 + v];
        h8[v] = keep + __shfl_xor(send, 2);
    }
    const bool hi1 = (l4 & 1);
    float k4[4];
#pragma unroll
    for (int v = 0; v < 4; ++v) {
        float keep = hi1 ? h8[4 + v] : h8[v];
        float send = hi1 ? h8[v] : h8[4 + v];
        k4[v] = keep + __shfl_xor(send, 1);
    }
    const int k0 = l4 * 4;
    float o0 = 0.0f, o1 = 0.0f;
#pragma unroll
    for (int kk = 0; kk < 4; ++kk) {
        float v = fmaxf(fmaf(k4[kk], di, sB3[k0 + kk]), 0.0f);
        o0 = fmaf(v, sW4[2 * (k0 + kk)], o0);
        o1 = fmaf(v, sW4[2 * (k0 + kk) + 1], o1);
    }
    o0 += __shfl_xor(o0, 1); o0 += __shfl_xor(o0, 2);
    o1 += __shfl_xor(o1, 1); o1 += __shfl_xor(o1, 2);
    if (l4 == 0)
        *reinterpret_cast<__half2*>(h4s + 2LL * node) = __floats2half2_rn(o0 * di, o1 * di);
}

// ---------------- final: F=2 aggregation + log_softmax (4 lanes/node) --------
__global__ __launch_bounds__(256) void agg2_lsm_kernel(
    const __half* __restrict__ hs, const float* __restrict__ dinv,
    const int* __restrict__ sorted_src, const int2* __restrict__ ends,
    const float* __restrict__ b, float* __restrict__ out, int n) {
    long long gt = (long long)blockIdx.x * 256 + threadIdx.x;
    int node = (int)(gt >> 2);
    int l4   = (int)(gt & 3);
    if (node >= n) return;
    int2 be = ends[node];
    float ax = 0.0f, ay = 0.0f;
    if (l4 == 3) {
        float2 r = __half22float2(*reinterpret_cast<const __half2*>(hs + 2LL * node));
        ax += r.x; ay += r.y;
    }
    for (int e = be.x + l4; e < be.y; e += 4) {
        int s = sorted_src[e];
        float2 r = __half22float2(*reinterpret_cast<const __half2*>(hs + 2LL * s));
        ax += r.x; ay += r.y;
    }
    ax += __shfl_xor(ax, 1); ax += __shfl_xor(ax, 2);
    ay += __shfl_xor(ay, 1); ay += __shfl_xor(ay, 2);
    if (l4 == 0) {
        float di = dinv[node];
        float a = ax * di + b[0];
        float c = ay * di + b[1];
        float m = fmaxf(a, c);
        float lse = m + logf(expf(a - m) + expf(c - m));
        float2 r = make_float2(a - lse, c - lse);
        *reinterpret_cast<float2*>(out + 2LL * node) = r;
    }
}

static inline int cdiv_ll(long long a, int b) { return (int)((a + b - 1) / b); }
static inline char* align16(char* p) { return (char*)(((uintptr_t)p + 15) & ~(uintptr_t)15); }

extern "C" void kernel_launch(void* const* d_in, const int* in_sizes, int n_in,
                              void* d_out, int out_size, void* d_ws, size_t ws_size,
                              hipStream_t stream) {
    (void)n_in; (void)out_size; (void)ws_size;

    const float* x  = (const float*)d_in[0];      // [N,18]
    const int*   ei = (const int*)d_in[1];        // [2,E]
    const float* W1 = (const float*)d_in[2];
    const float* b1 = (const float*)d_in[3];
    const float* W2 = (const float*)d_in[4];
    const float* b2 = (const float*)d_in[5];
    const float* W3 = (const float*)d_in[6];
    const float* b3 = (const float*)d_in[7];
    const float* W4 = (const float*)d_in[8];
    const float* b4 = (const float*)d_in[9];

    const int n = in_sizes[0] / 18;               // 100000
    const int E = in_sizes[1] / 2;                // 1600000
    const int* src = ei;
    const int* dst = ei + E;
    const int nbuck = (n + 255) >> NBUCK_SHIFT;   // 391

    // ---- workspace layout (16B-aligned regions) ----
    char* p = (char*)d_ws;
    int*    gcur       = (int*)p;            p = align16(p + 512 * 4);
    int2*   ends       = (int2*)p;           p = align16(p + (size_t)n * 8);
    float*  dinv       = (float*)p;          p = align16(p + (size_t)n * 4);
    int*    sorted_src = (int*)p;            p = align16(p + (size_t)nbuck * CAP * 4);  // 12.8MB padded
    unsigned int* bucketed = (unsigned int*)p; p = align16(p + (size_t)nbuck * CAP * 4); // 12.8MB padded
    __half* xs         = (__half*)p;         p = align16(p + (size_t)n * 24 * 2);  // 4.8MB
    __half* h2s        = (__half*)p;         p = align16(p + (size_t)n * 32 * 2);  // 6.4MB
    __half* h3s        = (__half*)p;         p = align16(p + (size_t)n * 16 * 2);  // 3.2MB
    __half* h4s        = (__half*)p;         p = align16(p + (size_t)n * 2 * 2);   // 0.4MB

    const int B = 256;
    const int NODE_BLOCKS  = cdiv_ll(n, B);
    const int NODE4_BLOCKS = cdiv_ll(4LL * n, B);

    // ---- CSR-by-dst via fixed-capacity bucketed sort (no hist/scan) ----
    init_gcur_kernel<<<1, 512, 0, stream>>>(gcur, nbuck);
    partition_kernel<<<cdiv_ll(E, PART_CHUNK), B, 0, stream>>>(src, dst, gcur, bucketed, E, nbuck);
    csr_kernel<<<nbuck, B, 0, stream>>>(bucketed, gcur, ends, dinv, sorted_src, n);

    // ---- fused pipeline (4 lanes/node) ----
    scale_pad18_kernel<<<NODE_BLOCKS, B, 0, stream>>>(x, dinv, xs, n);
    layer12_kernel<<<NODE4_BLOCKS, B, 0, stream>>>(xs, dinv, sorted_src, ends, W1, b1, W2, h2s, n);
    layer3_kernel<<<NODE4_BLOCKS, B, 0, stream>>>(h2s, dinv, sorted_src, ends, b2, W3, h3s, n);
    layer4_kernel<<<NODE4_BLOCKS, B, 0, stream>>>(h3s, dinv, sorted_src, ends, b3, W4, h4s, n);
    agg2_lsm_kernel<<<NODE4_BLOCKS, B, 0, stream>>>(h4s, dinv, sorted_src, ends, b4, (float*)d_out, n);
}

// Round 10
// 205.900 us; speedup vs baseline: 1.6088x; 1.0015x over previous
//
#include <hip/hip_runtime.h>
#include <hip/hip_bf16.h>
#include <hip/hip_fp16.h>

// ============================================================================
// GCN forward. CSR-by-dst via fixed-capacity bucketed counting sort (no
// histogram/scan); fused gather+dense layer kernels, 8 lanes/node:
//   - gather: edge-split across 8 lanes, __shfl_xor (DPP/swizzle) combine.
//   - dense: LDS weights via ds_read_b128/b64, conflict-free lane->bank maps:
//       * L12 stage-1 (18->64): j-split stride 8 floats -> 2-way (free).
//       * L12 stage-2 (64->32): f-split stride 4 floats -> banks perfectly
//         partitioned (lane l8 covers banks 4*l8..4*l8+3).
//       * L3 (32->16): f-split stride 2 floats -> conflict-free b64.
//     hidden/k values exchanged intra-octet via __shfl_xor(1..7), no LDS.
//   - scale/pad of x folded into csr_kernel (owns a thread per node + dinv).
//
// Algebra: A_hat(xW) = (A_hat x)W, normalization factored as
//   out[d] = dinv[d] * ( sum_{s in N(d)} hs[s] + hs[d] ) + b,  hs = h*dinv[row]
// hs tables fp16 (fp32 accumulation): xs=4.8MB, h2s=6.4MB, h3s=3.2MB.
// ============================================================================

#define NBUCK_SHIFT 8            // 256 nodes per bucket
#define CAP         8192         // bucket capacity (avg 4096, sigma ~64)
#define PART_CHUNK  4096         // edges per partition block (256 thr x 16)

// ---------------- init per-bucket cursors to fixed bases ----------------
__global__ void init_gcur_kernel(int* __restrict__ gcur, int nbuck) {
    int i = threadIdx.x;
    if (i < nbuck) gcur[i] = i * CAP;
}

// ---------------- partition edges into fixed-capacity buckets ----------------
// staged word: (src << 8) | (dst & 255)
__global__ __launch_bounds__(256) void partition_kernel(const int* __restrict__ src,
                                                        const int* __restrict__ dst,
                                                        int* __restrict__ gcur,
                                                        unsigned int* __restrict__ bucketed,
                                                        int n_edges, int nbuck) {
    __shared__ int cnt[512];
    __shared__ int base[512];
    const int t = threadIdx.x;
    for (int i = t; i < 512; i += 256) cnt[i] = 0;
    __syncthreads();
    long long start = (long long)blockIdx.x * PART_CHUNK;
    int sv[16], dv[16], bv[16];
#pragma unroll
    for (int k = 0; k < 16; ++k) {
        long long e = start + (long long)k * 256 + t;
        bool ok = e < n_edges;
        sv[k] = ok ? src[e] : 0;
        dv[k] = ok ? dst[e] : 0;
        bv[k] = ok ? (dv[k] >> NBUCK_SHIFT) : -1;
        if (ok) atomicAdd(&cnt[bv[k]], 1);
    }
    __syncthreads();
    for (int i = t; i < nbuck; i += 256) {
        int c = cnt[i];
        base[i] = c ? atomicAdd(&gcur[i], c) : 0;
    }
    __syncthreads();
    for (int i = t; i < 512; i += 256) cnt[i] = 0;   // reuse as running cursor
    __syncthreads();
#pragma unroll
    for (int k = 0; k < 16; ++k) {
        if (bv[k] >= 0) {
            int pos = base[bv[k]] + atomicAdd(&cnt[bv[k]], 1);
            bucketed[pos] = ((unsigned int)sv[k] << 8) | (unsigned int)(dv[k] & 255);
        }
    }
}

// ---------------- per-bucket CSR finalize + x scale/pad ----------------------
// ends=(beg,end), dinv, sorted_src placement, and xs = half(x*dinv) padded 24.
__device__ inline float4 pack8_dev(const float* v) {
    float4 out;
    __half2* h2 = reinterpret_cast<__half2*>(&out);
#pragma unroll
    for (int j = 0; j < 4; ++j) h2[j] = __floats2half2_rn(v[2 * j], v[2 * j + 1]);
    return out;
}

__global__ __launch_bounds__(256) void csr_kernel(const unsigned int* __restrict__ bucketed,
                                                  const int* __restrict__ gcur,
                                                  const float* __restrict__ x,
                                                  int2* __restrict__ ends,
                                                  float* __restrict__ dinv,
                                                  int* __restrict__ sorted_src,
                                                  __half* __restrict__ xs,
                                                  int n) {
    __shared__ int ldeg[256];
    __shared__ int lscan[256];
    const int b = blockIdx.x;
    const int t = threadIdx.x;
    const int beg = b * CAP;
    const int end = gcur[b];                 // beg + count(bucket b)
    ldeg[t] = 0;
    __syncthreads();
    for (int e = beg + t; e < end; e += 256) {
        unsigned int p = bucketed[e];
        atomicAdd(&ldeg[p & 255u], 1);
    }
    __syncthreads();
    int v = ldeg[t];
    lscan[t] = v;
    __syncthreads();
    for (int off = 1; off < 256; off <<= 1) {
        int xv = (t >= off) ? lscan[t - off] : 0;
        __syncthreads();
        lscan[t] += xv;
        __syncthreads();
    }
    int excl = lscan[t] - v;                 // exclusive scan
    int node = (b << NBUCK_SHIFT) + t;
    float di = rsqrtf((float)v + 1.0f);      // +1 self-loop
    if (node < n) {
        ends[node] = make_int2(beg + excl, beg + excl + v);
        dinv[node] = di;
        // xs row = half(x * di), padded to 24
        const float* xr = x + (long long)node * 18;
        float vv[24];
#pragma unroll
        for (int k = 0; k < 18; ++k) vv[k] = xr[k] * di;
#pragma unroll
        for (int k = 18; k < 24; ++k) vv[k] = 0.0f;
        float4* o = reinterpret_cast<float4*>(xs + (long long)node * 24);
        o[0] = pack8_dev(vv);
        o[1] = pack8_dev(vv + 8);
        o[2] = pack8_dev(vv + 16);
    }
    __syncthreads();
    lscan[t] = beg + excl;                   // reuse as placement cursor
    __syncthreads();
    for (int e = beg + t; e < end; e += 256) {
        unsigned int p = bucketed[e];
        int pos = atomicAdd(&lscan[p & 255u], 1);
        sorted_src[pos] = (int)(p >> 8);
    }
}

// ---------------- helpers ----------------
__device__ inline void acc8(float* acc, float4 raw) {
    const __half2* h2 = reinterpret_cast<const __half2*>(&raw);
#pragma unroll
    for (int j = 0; j < 4; ++j) {
        float2 v = __half22float2(h2[j]);
        acc[2 * j]     += v.x;
        acc[2 * j + 1] += v.y;
    }
}

// ---------------- fused layer 1+2 (8 lanes/node) ----------------------------
// gather(18, edge-split) -> allreduce -> 18->64 relu (j-split 8, b128 LDS)
// -> 64->32 (f-split 8, octet shfl exchange, b128 LDS) -> lane stores 4 fp16.
__global__ __launch_bounds__(256) void layer12_kernel(
    const __half* __restrict__ xs, const float* __restrict__ dinv,
    const int* __restrict__ sorted_src, const int2* __restrict__ ends,
    const float* __restrict__ W1, const float* __restrict__ b1,
    const float* __restrict__ W2, __half* __restrict__ h2s, int n) {
    __shared__ float sW1[18 * 64];   // j-stride 8 -> 2-way (free)
    __shared__ float sB1[64];
    __shared__ float sW2[64 * 32];   // f-stride 4 -> banks partitioned, clean
    for (int i = threadIdx.x; i < 18 * 64; i += 256) sW1[i] = W1[i];
    for (int i = threadIdx.x; i < 64; i += 256) sB1[i] = b1[i];
    for (int i = threadIdx.x; i < 64 * 32; i += 256) sW2[i] = W2[i];
    __syncthreads();
    const float4* sW1v = reinterpret_cast<const float4*>(sW1);
    const float4* sW2v = reinterpret_cast<const float4*>(sW2);

    long long gt = (long long)blockIdx.x * 256 + threadIdx.x;
    int node = (int)(gt >> 3);
    int l8   = (int)(gt & 7);
    if (node >= n) return;
    int2 be = ends[node];
    float di = dinv[node];

    // ---- gather (edge-split over 8 lanes) ----
    float acc[24];
#pragma unroll
    for (int j = 0; j < 24; ++j) acc[j] = 0.0f;
    if (l8 == 7) {   // lane 7 has the fewest edges; give it the self row
        const float4* pp = reinterpret_cast<const float4*>(xs + (long long)node * 24);
        acc8(acc, pp[0]); acc8(acc + 8, pp[1]); acc8(acc + 16, pp[2]);
    }
    for (int e = be.x + l8; e < be.y; e += 8) {
        int s = sorted_src[e];
        const float4* pp = reinterpret_cast<const float4*>(xs + (long long)s * 24);
        acc8(acc, pp[0]); acc8(acc + 8, pp[1]); acc8(acc + 16, pp[2]);
    }
#pragma unroll
    for (int j = 0; j < 18; ++j) {       // all-reduce over octet
        acc[j] += __shfl_xor(acc[j], 1);
        acc[j] += __shfl_xor(acc[j], 2);
        acc[j] += __shfl_xor(acc[j], 4);
        acc[j] *= di;                    // fold *di once here
    }

    // ---- stage 1: hidden slice j0 = l8*8 ----
    const int j0 = l8 * 8;
    float hid[8];
#pragma unroll
    for (int jj = 0; jj < 8; ++jj) hid[jj] = sB1[j0 + jj];
#pragma unroll
    for (int k = 0; k < 18; ++k) {
        float ak = acc[k];
#pragma unroll
        for (int q = 0; q < 2; ++q) {
            float4 w = sW1v[k * 16 + l8 * 2 + q];
            hid[4 * q]     = fmaf(ak, w.x, hid[4 * q]);
            hid[4 * q + 1] = fmaf(ak, w.y, hid[4 * q + 1]);
            hid[4 * q + 2] = fmaf(ak, w.z, hid[4 * q + 2]);
            hid[4 * q + 3] = fmaf(ak, w.w, hid[4 * q + 3]);
        }
    }
#pragma unroll
    for (int jj = 0; jj < 8; ++jj) hid[jj] = fmaxf(hid[jj], 0.0f);

    // ---- stage 2: f-split (f0 = l8*4); hid exchanged via octet shfl ----
    float out[4] = {0.0f, 0.0f, 0.0f, 0.0f};
#pragma unroll
    for (int jj = 0; jj < 8; ++jj) {
        float hv[8];
        hv[0] = hid[jj];
#pragma unroll
        for (int m = 1; m < 8; ++m) hv[m] = __shfl_xor(hv[0], m);
#pragma unroll
        for (int m = 0; m < 8; ++m) {
            int j = (l8 ^ m) * 8 + jj;
            float4 w = sW2v[j * 8 + l8];          // = (j*32 + l8*4)/4
            out[0] = fmaf(hv[m], w.x, out[0]);
            out[1] = fmaf(hv[m], w.y, out[1]);
            out[2] = fmaf(hv[m], w.z, out[2]);
            out[3] = fmaf(hv[m], w.w, out[3]);
        }
    }
    union { float2 f2; __half2 h2[2]; } u;
    u.h2[0] = __floats2half2_rn(out[0] * di, out[1] * di);
    u.h2[1] = __floats2half2_rn(out[2] * di, out[3] * di);
    *reinterpret_cast<float2*>(h2s + (long long)node * 32 + l8 * 4) = u.f2;
}

// ---------------- fused layer 3 (8 lanes/node) ------------------------------
// gather(32) -> reduce-scatter (lane owns 4 k's) -> relu(+b2)
// -> 32->16 f-split (f0=l8*2, b64 LDS, octet shfl) -> lane stores 2 fp16.
__global__ __launch_bounds__(256) void layer3_kernel(
    const __half* __restrict__ h2s, const float* __restrict__ dinv,
    const int* __restrict__ sorted_src, const int2* __restrict__ ends,
    const float* __restrict__ b2, const float* __restrict__ W3,
    __half* __restrict__ h3s, int n) {
    __shared__ float sW3[32 * 16];   // f-stride 2 -> conflict-free b64
    __shared__ float sB2[32];
    for (int i = threadIdx.x; i < 32 * 16; i += 256) sW3[i] = W3[i];
    for (int i = threadIdx.x; i < 32; i += 256) sB2[i] = b2[i];
    __syncthreads();
    const float2* sW3v = reinterpret_cast<const float2*>(sW3);

    long long gt = (long long)blockIdx.x * 256 + threadIdx.x;
    int node = (int)(gt >> 3);
    int l8   = (int)(gt & 7);
    if (node >= n) return;
    int2 be = ends[node];
    float di = dinv[node];

    float acc[32];
#pragma unroll
    for (int j = 0; j < 32; ++j) acc[j] = 0.0f;
    if (l8 == 7) {
        const float4* pp = reinterpret_cast<const float4*>(h2s + (long long)node * 32);
        acc8(acc, pp[0]); acc8(acc + 8, pp[1]); acc8(acc + 16, pp[2]); acc8(acc + 24, pp[3]);
    }
    for (int e = be.x + l8; e < be.y; e += 8) {
        int s = sorted_src[e];
        const float4* pp = reinterpret_cast<const float4*>(h2s + (long long)s * 32);
        acc8(acc, pp[0]); acc8(acc + 8, pp[1]); acc8(acc + 16, pp[2]); acc8(acc + 24, pp[3]);
    }
    // reduce-scatter acc[32] over octet -> lane owns k in [4*l8, 4*l8+4)
    const bool hi4 = (l8 & 4);
    float h16[16];
#pragma unroll
    for (int v = 0; v < 16; ++v) {
        float keep = hi4 ? acc[16 + v] : acc[v];
        float send = hi4 ? acc[v] : acc[16 + v];
        h16[v] = keep + __shfl_xor(send, 4);
    }
    const bool hi2 = (l8 & 2);
    float h8[8];
#pragma unroll
    for (int v = 0; v < 8; ++v) {
        float keep = hi2 ? h16[8 + v] : h16[v];
        float send = hi2 ? h16[v] : h16[8 + v];
        h8[v] = keep + __shfl_xor(send, 2);
    }
    const bool hi1 = (l8 & 1);
    float k4[4];
#pragma unroll
    for (int v = 0; v < 4; ++v) {
        float keep = hi1 ? h8[4 + v] : h8[v];
        float send = hi1 ? h8[v] : h8[4 + v];
        k4[v] = keep + __shfl_xor(send, 1);
    }

    // ---- dense: f-split (f0 = l8*2); k-values exchanged via octet shfl ----
    const int k0 = l8 * 4;
    float o0 = 0.0f, o1 = 0.0f;
#pragma unroll
    for (int kk = 0; kk < 4; ++kk) {
        float vv[8];
        vv[0] = fmaxf(fmaf(k4[kk], di, sB2[k0 + kk]), 0.0f);  // relu(acc*di+b2)
#pragma unroll
        for (int m = 1; m < 8; ++m) vv[m] = __shfl_xor(vv[0], m);
#pragma unroll
        for (int m = 0; m < 8; ++m) {
            int k = (l8 ^ m) * 4 + kk;
            float2 w = sW3v[k * 8 + l8];          // = (k*16 + l8*2)/2
            o0 = fmaf(vv[m], w.x, o0);
            o1 = fmaf(vv[m], w.y, o1);
        }
    }
    *reinterpret_cast<__half2*>(h3s + (long long)node * 16 + l8 * 2) =
        __floats2half2_rn(o0 * di, o1 * di);
}

// ---------------- fused layer 4 (8 lanes/node, tiny weights) -----------------
__global__ __launch_bounds__(256) void layer4_kernel(
    const __half* __restrict__ h3s, const float* __restrict__ dinv,
    const int* __restrict__ sorted_src, const int2* __restrict__ ends,
    const float* __restrict__ b3, const float* __restrict__ W4,
    __half* __restrict__ h4s, int n) {
    __shared__ float sW4[32];
    __shared__ float sB3[16];
    for (int i = threadIdx.x; i < 32; i += 256) sW4[i] = W4[i];
    for (int i = threadIdx.x; i < 16; i += 256) sB3[i] = b3[i];
    __syncthreads();

    long long gt = (long long)blockIdx.x * 256 + threadIdx.x;
    int node = (int)(gt >> 3);
    int l8   = (int)(gt & 7);
    if (node >= n) return;
    int2 be = ends[node];
    float di = dinv[node];

    float acc[16];
#pragma unroll
    for (int j = 0; j < 16; ++j) acc[j] = 0.0f;
    if (l8 == 7) {
        const float4* pp = reinterpret_cast<const float4*>(h3s + (long long)node * 16);
        acc8(acc, pp[0]); acc8(acc + 8, pp[1]);
    }
    for (int e = be.x + l8; e < be.y; e += 8) {
        int s = sorted_src[e];
        const float4* pp = reinterpret_cast<const float4*>(h3s + (long long)s * 16);
        acc8(acc, pp[0]); acc8(acc + 8, pp[1]);
    }
    // reduce-scatter acc[16] over octet -> lane owns k in [2*l8, 2*l8+2)
    const bool hi4 = (l8 & 4);
    float h8[8];
#pragma unroll
    for (int v = 0; v < 8; ++v) {
        float keep = hi4 ? acc[8 + v] : acc[v];
        float send = hi4 ? acc[v] : acc[8 + v];
        h8[v] = keep + __shfl_xor(send, 4);
    }
    const bool hi2 = (l8 & 2);
    float h4v[4];
#pragma unroll
    for (int v = 0; v < 4; ++v) {
        float keep = hi2 ? h8[4 + v] : h8[v];
        float send = hi2 ? h8[v] : h8[4 + v];
        h4v[v] = keep + __shfl_xor(send, 2);
    }
    const bool hi1 = (l8 & 1);
    float k2[2];
#pragma unroll
    for (int v = 0; v < 2; ++v) {
        float keep = hi1 ? h4v[2 + v] : h4v[v];
        float send = hi1 ? h4v[v] : h4v[2 + v];
        k2[v] = keep + __shfl_xor(send, 1);
    }
    const int k0 = l8 * 2;
    float o0 = 0.0f, o1 = 0.0f;
#pragma unroll
    for (int kk = 0; kk < 2; ++kk) {
        float v = fmaxf(fmaf(k2[kk], di, sB3[k0 + kk]), 0.0f);
        o0 = fmaf(v, sW4[2 * (k0 + kk)], o0);
        o1 = fmaf(v, sW4[2 * (k0 + kk) + 1], o1);
    }
    o0 += __shfl_xor(o0, 1); o0 += __shfl_xor(o0, 2); o0 += __shfl_xor(o0, 4);
    o1 += __shfl_xor(o1, 1); o1 += __shfl_xor(o1, 2); o1 += __shfl_xor(o1, 4);
    if (l8 == 0)
        *reinterpret_cast<__half2*>(h4s + 2LL * node) = __floats2half2_rn(o0 * di, o1 * di);
}

// ---------------- final: F=2 aggregation + log_softmax (8 lanes/node) --------
__global__ __launch_bounds__(256) void agg2_lsm_kernel(
    const __half* __restrict__ hs, const float* __restrict__ dinv,
    const int* __restrict__ sorted_src, const int2* __restrict__ ends,
    const float* __restrict__ b, float* __restrict__ out, int n) {
    long long gt = (long long)blockIdx.x * 256 + threadIdx.x;
    int node = (int)(gt >> 3);
    int l8   = (int)(gt & 7);
    if (node >= n) return;
    int2 be = ends[node];
    float ax = 0.0f, ay = 0.0f;
    if (l8 == 7) {
        float2 r = __half22float2(*reinterpret_cast<const __half2*>(hs + 2LL * node));
        ax += r.x; ay += r.y;
    }
    for (int e = be.x + l8; e < be.y; e += 8) {
        int s = sorted_src[e];
        float2 r = __half22float2(*reinterpret_cast<const __half2*>(hs + 2LL * s));
        ax += r.x; ay += r.y;
    }
    ax += __shfl_xor(ax, 1); ax += __shfl_xor(ax, 2); ax += __shfl_xor(ax, 4);
    ay += __shfl_xor(ay, 1); ay += __shfl_xor(ay, 2); ay += __shfl_xor(ay, 4);
    if (l8 == 0) {
        float di = dinv[node];
        float a = ax * di + b[0];
        float c = ay * di + b[1];
        float m = fmaxf(a, c);
        float lse = m + logf(expf(a - m) + expf(c - m));
        float2 r = make_float2(a - lse, c - lse);
        *reinterpret_cast<float2*>(out + 2LL * node) = r;
    }
}

static inline int cdiv_ll(long long a, int b) { return (int)((a + b - 1) / b); }
static inline char* align16(char* p) { return (char*)(((uintptr_t)p + 15) & ~(uintptr_t)15); }

extern "C" void kernel_launch(void* const* d_in, const int* in_sizes, int n_in,
                              void* d_out, int out_size, void* d_ws, size_t ws_size,
                              hipStream_t stream) {
    (void)n_in; (void)out_size; (void)ws_size;

    const float* x  = (const float*)d_in[0];      // [N,18]
    const int*   ei = (const int*)d_in[1];        // [2,E]
    const float* W1 = (const float*)d_in[2];
    const float* b1 = (const float*)d_in[3];
    const float* W2 = (const float*)d_in[4];
    const float* b2 = (const float*)d_in[5];
    const float* W3 = (const float*)d_in[6];
    const float* b3 = (const float*)d_in[7];
    const float* W4 = (const float*)d_in[8];
    const float* b4 = (const float*)d_in[9];

    const int n = in_sizes[0] / 18;               // 100000
    const int E = in_sizes[1] / 2;                // 1600000
    const int* src = ei;
    const int* dst = ei + E;
    const int nbuck = (n + 255) >> NBUCK_SHIFT;   // 391

    // ---- workspace layout (16B-aligned regions) ----
    char* p = (char*)d_ws;
    int*    gcur       = (int*)p;            p = align16(p + 512 * 4);
    int2*   ends       = (int2*)p;           p = align16(p + (size_t)n * 8);
    float*  dinv       = (float*)p;          p = align16(p + (size_t)n * 4);
    int*    sorted_src = (int*)p;            p = align16(p + (size_t)nbuck * CAP * 4);  // 12.8MB padded
    unsigned int* bucketed = (unsigned int*)p; p = align16(p + (size_t)nbuck * CAP * 4); // 12.8MB padded
    __half* xs         = (__half*)p;         p = align16(p + (size_t)n * 24 * 2);  // 4.8MB
    __half* h2s        = (__half*)p;         p = align16(p + (size_t)n * 32 * 2);  // 6.4MB
    __half* h3s        = (__half*)p;         p = align16(p + (size_t)n * 16 * 2);  // 3.2MB
    __half* h4s        = (__half*)p;         p = align16(p + (size_t)n * 2 * 2);   // 0.4MB

    const int B = 256;
    const int NODE8_BLOCKS = cdiv_ll(8LL * n, B);

    // ---- CSR-by-dst via fixed-capacity bucketed sort (no hist/scan) ----
    init_gcur_kernel<<<1, 512, 0, stream>>>(gcur, nbuck);
    partition_kernel<<<cdiv_ll(E, PART_CHUNK), B, 0, stream>>>(src, dst, gcur, bucketed, E, nbuck);
    csr_kernel<<<nbuck, B, 0, stream>>>(bucketed, gcur, x, ends, dinv, sorted_src, xs, n);

    // ---- fused pipeline (8 lanes/node) ----
    layer12_kernel<<<NODE8_BLOCKS, B, 0, stream>>>(xs, dinv, sorted_src, ends, W1, b1, W2, h2s, n);
    layer3_kernel<<<NODE8_BLOCKS, B, 0, stream>>>(h2s, dinv, sorted_src, ends, b2, W3, h3s, n);
    layer4_kernel<<<NODE8_BLOCKS, B, 0, stream>>>(h3s, dinv, sorted_src, ends, b3, W4, h4s, n);
    agg2_lsm_kernel<<<NODE8_BLOCKS, B, 0, stream>>>(h4s, dinv, sorted_src, ends, b4, (float*)d_out, n);
}